// Round 1
// 122.705 us; speedup vs baseline: 1.0141x; 1.0141x over previous
//
#include <hip/hip_runtime.h>
#include <hip/hip_bf16.h>
#include <stdint.h>

// NonLocalBlock, fp32 in/out. B=4, N=4096, C=256, D=32.
// v7: attn rewritten barrier-free. Operand-swapped S^T = mfma(Q, K) keeps
// P^T lane-local (T12 trick); PV uses 16x16x16 MFMA with V^T A-frags loaded
// straight from vT. No LDS / no __syncthreads in the main loop; one 34 KB
// cross-wave O^T reduce at the end. qkv/out kernels unchanged from v6.
// ~90 us of total dur is harness ws-poison fill (fixed overhead).

typedef __attribute__((ext_vector_type(8))) short bf16x8;
typedef __attribute__((ext_vector_type(4))) short bf16x4;
typedef __attribute__((ext_vector_type(4))) float f32x4;
typedef unsigned short ushort_t;

static __device__ __forceinline__ ushort_t f2bf(float f) {
    __hip_bfloat16 h = __float2bfloat16(f);
    return __builtin_bit_cast(ushort_t, h);
}
static __device__ __forceinline__ float bf2f(ushort_t u) {
    return __bfloat162float(__builtin_bit_cast(__hip_bfloat16, u));
}

static __device__ __forceinline__ f32x4 mfma16bf(bf16x4 a, bf16x4 b, f32x4 c) {
#if __has_builtin(__builtin_amdgcn_mfma_f32_16x16x16bf16_1k)
    return __builtin_amdgcn_mfma_f32_16x16x16bf16_1k(a, b, c, 0, 0, 0);
#else
    f32x4 d;
    asm("v_mfma_f32_16x16x16_bf16 %0, %1, %2, %3"
        : "=v"(d) : "v"(a), "v"(b), "v"(c));
    return d;
#endif
}

#define NROWS 16384
#define NTOK  4096
#define QKS   40   // q/k LDS row stride (ushorts): 80 B, 16B-aligned (K1 only)
#define OPART (NROWS * 32)   // per-chunk o partial (fp32 elems)

// ---------------- K1: QKV projection via split-bf16 MFMA ----------------
// 32 rows/block, grid 512 (2 blocks/CU). Wave w: row-group w&1, col-groups
// (w>>1)+{0,2,4}. W fp32 read per-lane (L1-hot), split hi/lo in regs.
__global__ __launch_bounds__(256) void qkv_kernel(
    const float* __restrict__ x,
    const float* __restrict__ Wf, const float* __restrict__ Wg,
    const float* __restrict__ Wh,
    ushort_t* __restrict__ qh,
    ushort_t* __restrict__ kh, ushort_t* __restrict__ kl,
    ushort_t* __restrict__ vT)   // [b][d][m] = [4][32][4096]
{
    __shared__ __align__(16) ushort_t xh[32 * QKS];
    __shared__ __align__(16) ushort_t xl[32 * QKS];

    const int tid  = threadIdx.x;
    const int wave = tid >> 6;
    const int lane = tid & 63;
    const int ln15 = lane & 15;
    const int quad = lane >> 4;
    const int row0 = blockIdx.x * 32;
    const int rg     = wave & 1;
    const int cgbase = wave >> 1;
    const int r  = tid >> 3;        // staging row 0..31
    const int pp = (tid & 7) * 4;   // staging col (floats)

    f32x4 acc[3];
    #pragma unroll
    for (int ci = 0; ci < 3; ++ci) acc[ci] = (f32x4){0.f, 0.f, 0.f, 0.f};

    float4 xa = *reinterpret_cast<const float4*>(&x[(row0 + r) * 256 + pp]);

    for (int k0 = 0; k0 < 256; k0 += 32) {
        // B fragments: read W fp32 directly, split hi/lo in registers
        bf16x8 bh[3], bl[3];
        #pragma unroll
        for (int ci = 0; ci < 3; ++ci) {
            int cg = cgbase + ci * 2;
            const float* Wsrc = (cg < 2) ? Wf : (cg < 4) ? Wg : Wh;
            int c = (cg & 1) * 16 + ln15;
            ushort_t hv8[8], lv8[8];
            #pragma unroll
            for (int j = 0; j < 8; ++j) {
                float w = Wsrc[(k0 + quad * 8 + j) * 32 + c];
                ushort_t hi = f2bf(w);
                hv8[j] = hi;
                lv8[j] = f2bf(w - bf2f(hi));
            }
            bh[ci] = *reinterpret_cast<bf16x8*>(hv8);
            bl[ci] = *reinterpret_cast<bf16x8*>(lv8);
        }
        // split current x chunk
        float fv[4];
        *reinterpret_cast<float4*>(fv) = xa;
        ushort_t hv[4], lv[4];
        #pragma unroll
        for (int j = 0; j < 4; ++j) {
            hv[j] = f2bf(fv[j]);
            lv[j] = f2bf(fv[j] - bf2f(hv[j]));
        }
        __syncthreads();
        *reinterpret_cast<uint2*>(&xh[r * QKS + pp]) = *reinterpret_cast<uint2*>(hv);
        *reinterpret_cast<uint2*>(&xl[r * QKS + pp]) = *reinterpret_cast<uint2*>(lv);
        __syncthreads();
        if (k0 < 224)
            xa = *reinterpret_cast<const float4*>(&x[(row0 + r) * 256 + k0 + 32 + pp]);

        const bf16x8 ah = *reinterpret_cast<const bf16x8*>(
            &xh[(rg * 16 + ln15) * QKS + quad * 8]);
        const bf16x8 al = *reinterpret_cast<const bf16x8*>(
            &xl[(rg * 16 + ln15) * QKS + quad * 8]);
        #pragma unroll
        for (int ci = 0; ci < 3; ++ci) {
            acc[ci] = __builtin_amdgcn_mfma_f32_16x16x32_bf16(ah, bh[ci], acc[ci], 0, 0, 0);
            acc[ci] = __builtin_amdgcn_mfma_f32_16x16x32_bf16(al, bh[ci], acc[ci], 0, 0, 0);
            acc[ci] = __builtin_amdgcn_mfma_f32_16x16x32_bf16(ah, bl[ci], acc[ci], 0, 0, 0);
        }
    }

    #pragma unroll
    for (int ci = 0; ci < 3; ++ci) {
        int cg = cgbase + ci * 2;
        int cc = (cg & 1) * 16 + ln15;
        int rowb = row0 + rg * 16 + quad * 4;
        if (cg < 2) {
            #pragma unroll
            for (int rr = 0; rr < 4; ++rr)
                qh[(rowb + rr) * 32 + cc] = f2bf(acc[ci][rr]);
        } else if (cg < 4) {
            #pragma unroll
            for (int rr = 0; rr < 4; ++rr) {
                float val = acc[ci][rr];
                ushort_t hi = f2bf(val);
                kh[(rowb + rr) * 32 + cc] = hi;
                kl[(rowb + rr) * 32 + cc] = f2bf(val - bf2f(hi));
            }
        } else {
            // V pre-transposed: vT[b][d=cc][m], m = rowb..rowb+3 (same batch)
            int bb = row0 >> 12;
            int m  = (row0 & 4095) + rg * 16 + quad * 4;
            ushort4 h4;
            h4.x = f2bf(acc[ci][0]);
            h4.y = f2bf(acc[ci][1]);
            h4.z = f2bf(acc[ci][2]);
            h4.w = f2bf(acc[ci][3]);
            *reinterpret_cast<ushort4*>(&vT[bb * 131072 + cc * 4096 + m]) = h4;
        }
    }
}

// ---------------- K2: attention, barrier-free, S^T operand swap ----------------
// Grid 1024 = 256 rowtiles x 4 m-chunks, 4 waves/block. Waves split the m axis
// (wave w owns m-sub 16 within each 64-m iter). Per wave:
//   K frags (4 n-tiles x hi/lo) in regs, loaded once.
//   S^T[m',n] = mfma_16x16x32(A=Q, B=K): lane holds P^T[m'=quad*4+rr][n=ln15].
//   exp -> bf16 pack -> directly the B-frag of 16x16x16 PV MFMA:
//   O^T[d,n] += V^T[d,m'] * P^T[m',n], V^T A-frags as 8 B loads from vT.
// No LDS, no __syncthreads in the loop. One cross-wave O^T reduce at the end.
__global__ __launch_bounds__(256, 4) void attn_kernel(
    const ushort_t* __restrict__ qhg,
    const ushort_t* __restrict__ khg, const ushort_t* __restrict__ klg,
    const ushort_t* __restrict__ vT,
    float* __restrict__ o_part, float* __restrict__ l_part)
{
    __shared__ float Ored[4][32][65];   // [wave][d][n], stride 65 = conflict-free
    __shared__ float Lred[4][64];

    const int tid  = threadIdx.x;
    const int wave = tid >> 6;
    const int lane = tid & 63;
    const int ln15 = lane & 15;
    const int quad = lane >> 4;

    const int rowtile = blockIdx.x & 255;
    const int chunk   = blockIdx.x >> 8;     // 0..3
    const int b    = rowtile >> 6;
    const int n0   = (rowtile & 63) * 64;
    const int base = b * NTOK;
    const int bb   = b * 131072;             // vT batch offset

    // K fragments in registers (B-operand of S^T): lane needs K[n=t*16+ln15][c=quad*8..+7]
    bf16x8 khf[4], klf[4];
    #pragma unroll
    for (int t = 0; t < 4; ++t) {
        khf[t] = *reinterpret_cast<const bf16x8*>(
            &khg[(base + n0 + t * 16 + ln15) * 32 + quad * 8]);
        klf[t] = *reinterpret_cast<const bf16x8*>(
            &klg[(base + n0 + t * 16 + ln15) * 32 + quad * 8]);
    }

    f32x4 accO[2][4];   // [s01 = d-tile][t = n-tile]
    #pragma unroll
    for (int s01 = 0; s01 < 2; ++s01)
        #pragma unroll
        for (int t = 0; t < 4; ++t)
            accO[s01][t] = (f32x4){0.f, 0.f, 0.f, 0.f};
    float lacc[4] = {0.f, 0.f, 0.f, 0.f};

    // per-wave m walk: m = chunk*1024 + it*64 + wave*16 + {0..15}
    const int mbase = chunk * 1024 + wave * 16;
    const ushort_t* qp  = qhg + (size_t)(base + mbase + ln15) * 32 + quad * 8;
    const ushort_t* vp0 = vT + bb + ln15 * 4096 + mbase + quad * 4;
    const ushort_t* vp1 = vp0 + 16 * 4096;

    for (int it = 0; it < 16; ++it) {
        const bf16x8 qf  = *reinterpret_cast<const bf16x8*>(qp);   // A: Q[m=ln15][c]
        const bf16x4 va0 = *reinterpret_cast<const bf16x4*>(vp0);  // A: V^T[d=ln15][m']
        const bf16x4 va1 = *reinterpret_cast<const bf16x4*>(vp1);  // A: V^T[d=16+ln15][m']
        qp  += 64 * 32;
        vp0 += 64;
        vp1 += 64;

        #pragma unroll
        for (int t = 0; t < 4; ++t) {
            // S^T[m'][n] for n-tile t; lane: m'=quad*4+rr, n=t*16+ln15
            f32x4 s = __builtin_amdgcn_mfma_f32_16x16x32_bf16(
                qf, khf[t], (f32x4){0.f, 0.f, 0.f, 0.f}, 0, 0, 0);
            s = __builtin_amdgcn_mfma_f32_16x16x32_bf16(qf, klf[t], s, 0, 0, 0);

            float p0 = __expf(s[0]);
            float p1 = __expf(s[1]);
            float p2 = __expf(s[2]);
            float p3 = __expf(s[3]);
            lacc[t] += (p0 + p1) + (p2 + p3);

            ushort_t pu[4];
            pu[0] = f2bf(p0);
            pu[1] = f2bf(p1);
            pu[2] = f2bf(p2);
            pu[3] = f2bf(p3);
            const bf16x4 pb = *reinterpret_cast<bf16x4*>(pu);  // B: P^T[m'][n]

            accO[0][t] = mfma16bf(va0, pb, accO[0][t]);
            accO[1][t] = mfma16bf(va1, pb, accO[1][t]);
        }
    }

    // ---- cross-wave reduction ----
    // O^T: lane holds O^T[d = s01*16 + quad*4 + rr][n = t*16 + ln15]
    #pragma unroll
    for (int s01 = 0; s01 < 2; ++s01)
        #pragma unroll
        for (int t = 0; t < 4; ++t)
            #pragma unroll
            for (int rr = 0; rr < 4; ++rr)
                Ored[wave][s01 * 16 + quad * 4 + rr][t * 16 + ln15] = accO[s01][t][rr];

    // denominator: reduce over quads within wave
    #pragma unroll
    for (int t = 0; t < 4; ++t) {
        float v = lacc[t];
        v += __shfl_xor(v, 16);
        v += __shfl_xor(v, 32);
        if (quad == 0) Lred[wave][t * 16 + ln15] = v;
    }
    __syncthreads();

    const int rowb = base + n0;
    float* op = o_part + (size_t)chunk * OPART;
    #pragma unroll
    for (int e = 0; e < 8; ++e) {
        int idx = e * 256 + tid;      // 0..2047
        int d = idx & 31;
        int n = idx >> 5;
        float v = Ored[0][d][n] + Ored[1][d][n] + Ored[2][d][n] + Ored[3][d][n];
        op[(rowb + n) * 32 + d] = v;
    }
    if (tid < 64) {
        l_part[chunk * NROWS + rowb + tid] =
            Lred[0][tid] + Lred[1][tid] + Lred[2][tid] + Lred[3][tid];
    }
}

// ---------------- K3: out = gamma*((sum o_part / sum l)@Wv) + x ----------------
__global__ __launch_bounds__(256) void out_kernel(
    const float* __restrict__ o_part, const float* __restrict__ l_part,
    const float* __restrict__ Wv, const float* __restrict__ x,
    const float* __restrict__ gamma, float* __restrict__ out)
{
    __shared__ float wv[8192];
    __shared__ float orow[32][32];
    __shared__ float linv[32];
    const int tid  = threadIdx.x;
    const int row0 = blockIdx.x * 32;

    for (int i = tid; i < 8192; i += 256) wv[i] = Wv[i];
    for (int i = tid; i < 1024; i += 256) {
        int rr = i >> 5, d = i & 31;
        int idx = (row0 + rr) * 32 + d;
        orow[rr][d] = o_part[idx] + o_part[OPART + idx]
                    + o_part[2 * OPART + idx] + o_part[3 * OPART + idx];
    }
    if (tid < 32) {
        int row = row0 + tid;
        linv[tid] = 1.0f / (l_part[row] + l_part[NROWS + row]
                          + l_part[2 * NROWS + row] + l_part[3 * NROWS + row]);
    }
    __syncthreads();

    const float g = gamma[0];
    #pragma unroll 4
    for (int rc = 0; rc < 32; rc += 8) {
        float acc[8];
        #pragma unroll
        for (int rr = 0; rr < 8; ++rr) acc[rr] = 0.f;
        for (int d = 0; d < 32; ++d) {
            float wvd = wv[d * 256 + tid];
            #pragma unroll
            for (int rr = 0; rr < 8; ++rr) acc[rr] += orow[rc + rr][d] * wvd;
        }
        #pragma unroll
        for (int rr = 0; rr < 8; ++rr) {
            int row = row0 + rc + rr;
            out[row * 256 + tid] = g * acc[rr] * linv[rc + rr] + x[row * 256 + tid];
        }
    }
}

extern "C" void kernel_launch(void* const* d_in, const int* in_sizes, int n_in,
                              void* d_out, int out_size, void* d_ws, size_t ws_size,
                              hipStream_t stream)
{
    const float* x     = (const float*)d_in[0];
    const float* Wf    = (const float*)d_in[1];
    const float* Wg    = (const float*)d_in[2];
    const float* Wh    = (const float*)d_in[3];
    const float* Wv    = (const float*)d_in[4];
    const float* gamma = (const float*)d_in[5];
    float* out = (float*)d_out;

    // ws: qh,kh,kl,vT bf16 (1 MB each) + o_part fp32 4x2 MB + l_part 4x64 KB
    ushort_t* qh = (ushort_t*)d_ws;
    ushort_t* kh = qh + NROWS * 32;
    ushort_t* kl = kh + NROWS * 32;
    ushort_t* vT = kl + NROWS * 32;
    float* o_part = (float*)(vT + NROWS * 32);
    float* l_part = o_part + (size_t)4 * OPART;

    qkv_kernel<<<dim3(512), dim3(256), 0, stream>>>(x, Wf, Wg, Wh, qh, kh, kl, vT);
    attn_kernel<<<dim3(1024), dim3(256), 0, stream>>>(qh, kh, kl, vT, o_part, l_part);
    out_kernel<<<dim3(512), dim3(256), 0, stream>>>(o_part, l_part, Wv, x, gamma, out);
}

// Round 2
// 113.441 us; speedup vs baseline: 1.0970x; 1.0817x over previous
//
#include <hip/hip_runtime.h>
#include <hip/hip_bf16.h>
#include <stdint.h>

// NonLocalBlock, fp32 in/out. B=4, N=4096, C=256, D=32.
// v8: 2 graph nodes. attn now owns the FULL m range per block (no m-chunk
// split) and fuses the epilogue: denominator divide + @Wv + gamma*o + x.
// o_part/l_part and out_kernel are gone (~16 MB HBM round-trip removed).
// qh is pre-scaled by log2(e) in K1 so softmax uses raw v_exp_f32 (exp2),
// no per-element v_mul. Main loop stays barrier-free / LDS-free (v7 T12
// operand-swap structure). ~88 us of total dur is harness ws-poison fill.

typedef __attribute__((ext_vector_type(8))) short bf16x8;
typedef __attribute__((ext_vector_type(4))) short bf16x4;
typedef __attribute__((ext_vector_type(4))) float f32x4;
typedef unsigned short ushort_t;

static __device__ __forceinline__ ushort_t f2bf(float f) {
    __hip_bfloat16 h = __float2bfloat16(f);
    return __builtin_bit_cast(ushort_t, h);
}
static __device__ __forceinline__ float bf2f(ushort_t u) {
    return __bfloat162float(__builtin_bit_cast(__hip_bfloat16, u));
}

static __device__ __forceinline__ f32x4 mfma16bf(bf16x4 a, bf16x4 b, f32x4 c) {
#if __has_builtin(__builtin_amdgcn_mfma_f32_16x16x16bf16_1k)
    return __builtin_amdgcn_mfma_f32_16x16x16bf16_1k(a, b, c, 0, 0, 0);
#else
    f32x4 d;
    asm("v_mfma_f32_16x16x16_bf16 %0, %1, %2, %3"
        : "=v"(d) : "v"(a), "v"(b), "v"(c));
    return d;
#endif
}

static __device__ __forceinline__ float fexp2(float x) {
#if __has_builtin(__builtin_amdgcn_exp2f)
    return __builtin_amdgcn_exp2f(x);
#else
    return exp2f(x);
#endif
}

#define NROWS 16384
#define NTOK  4096
#define QKS   40   // q/k LDS row stride (ushorts): 80 B, 16B-aligned (K1 only)
#define LOG2E 1.44269504088896340736f

// ---------------- K1: QKV projection via split-bf16 MFMA ----------------
// 32 rows/block, grid 512 (2 blocks/CU). Wave w: row-group w&1, col-groups
// (w>>1)+{0,2,4}. W fp32 read per-lane (L1-hot), split hi/lo in regs.
// q output is pre-scaled by log2(e) so attn can use exp2 directly.
__global__ __launch_bounds__(256) void qkv_kernel(
    const float* __restrict__ x,
    const float* __restrict__ Wf, const float* __restrict__ Wg,
    const float* __restrict__ Wh,
    ushort_t* __restrict__ qh,
    ushort_t* __restrict__ kh, ushort_t* __restrict__ kl,
    ushort_t* __restrict__ vT)   // [b][d][m] = [4][32][4096]
{
    __shared__ __align__(16) ushort_t xh[32 * QKS];
    __shared__ __align__(16) ushort_t xl[32 * QKS];

    const int tid  = threadIdx.x;
    const int wave = tid >> 6;
    const int lane = tid & 63;
    const int ln15 = lane & 15;
    const int quad = lane >> 4;
    const int row0 = blockIdx.x * 32;
    const int rg     = wave & 1;
    const int cgbase = wave >> 1;
    const int r  = tid >> 3;        // staging row 0..31
    const int pp = (tid & 7) * 4;   // staging col (floats)

    f32x4 acc[3];
    #pragma unroll
    for (int ci = 0; ci < 3; ++ci) acc[ci] = (f32x4){0.f, 0.f, 0.f, 0.f};

    float4 xa = *reinterpret_cast<const float4*>(&x[(row0 + r) * 256 + pp]);

    for (int k0 = 0; k0 < 256; k0 += 32) {
        // B fragments: read W fp32 directly, split hi/lo in registers
        bf16x8 bh[3], bl[3];
        #pragma unroll
        for (int ci = 0; ci < 3; ++ci) {
            int cg = cgbase + ci * 2;
            const float* Wsrc = (cg < 2) ? Wf : (cg < 4) ? Wg : Wh;
            int c = (cg & 1) * 16 + ln15;
            ushort_t hv8[8], lv8[8];
            #pragma unroll
            for (int j = 0; j < 8; ++j) {
                float w = Wsrc[(k0 + quad * 8 + j) * 32 + c];
                ushort_t hi = f2bf(w);
                hv8[j] = hi;
                lv8[j] = f2bf(w - bf2f(hi));
            }
            bh[ci] = *reinterpret_cast<bf16x8*>(hv8);
            bl[ci] = *reinterpret_cast<bf16x8*>(lv8);
        }
        // split current x chunk
        float fv[4];
        *reinterpret_cast<float4*>(fv) = xa;
        ushort_t hv[4], lv[4];
        #pragma unroll
        for (int j = 0; j < 4; ++j) {
            hv[j] = f2bf(fv[j]);
            lv[j] = f2bf(fv[j] - bf2f(hv[j]));
        }
        __syncthreads();
        *reinterpret_cast<uint2*>(&xh[r * QKS + pp]) = *reinterpret_cast<uint2*>(hv);
        *reinterpret_cast<uint2*>(&xl[r * QKS + pp]) = *reinterpret_cast<uint2*>(lv);
        __syncthreads();
        if (k0 < 224)
            xa = *reinterpret_cast<const float4*>(&x[(row0 + r) * 256 + k0 + 32 + pp]);

        const bf16x8 ah = *reinterpret_cast<const bf16x8*>(
            &xh[(rg * 16 + ln15) * QKS + quad * 8]);
        const bf16x8 al = *reinterpret_cast<const bf16x8*>(
            &xl[(rg * 16 + ln15) * QKS + quad * 8]);
        #pragma unroll
        for (int ci = 0; ci < 3; ++ci) {
            acc[ci] = __builtin_amdgcn_mfma_f32_16x16x32_bf16(ah, bh[ci], acc[ci], 0, 0, 0);
            acc[ci] = __builtin_amdgcn_mfma_f32_16x16x32_bf16(al, bh[ci], acc[ci], 0, 0, 0);
            acc[ci] = __builtin_amdgcn_mfma_f32_16x16x32_bf16(ah, bl[ci], acc[ci], 0, 0, 0);
        }
    }

    #pragma unroll
    for (int ci = 0; ci < 3; ++ci) {
        int cg = cgbase + ci * 2;
        int cc = (cg & 1) * 16 + ln15;
        int rowb = row0 + rg * 16 + quad * 4;
        if (cg < 2) {
            #pragma unroll
            for (int rr = 0; rr < 4; ++rr)
                qh[(rowb + rr) * 32 + cc] = f2bf(acc[ci][rr] * LOG2E);
        } else if (cg < 4) {
            #pragma unroll
            for (int rr = 0; rr < 4; ++rr) {
                float val = acc[ci][rr];
                ushort_t hi = f2bf(val);
                kh[(rowb + rr) * 32 + cc] = hi;
                kl[(rowb + rr) * 32 + cc] = f2bf(val - bf2f(hi));
            }
        } else {
            // V pre-transposed: vT[b][d=cc][m], m = rowb..rowb+3 (same batch)
            int bb = row0 >> 12;
            int m  = (row0 & 4095) + rg * 16 + quad * 4;
            ushort4 h4;
            h4.x = f2bf(acc[ci][0]);
            h4.y = f2bf(acc[ci][1]);
            h4.z = f2bf(acc[ci][2]);
            h4.w = f2bf(acc[ci][3]);
            *reinterpret_cast<ushort4*>(&vT[bb * 131072 + cc * 4096 + m]) = h4;
        }
    }
}

// ---------------- K2: fused attention + output projection ----------------
// Grid 256 = 4 batches x 64 rowtiles, 512 threads (8 waves). Wave w owns
// m-sub 16 of each 128-m iter, 32 iters (full m range). Per wave:
//   K frags (4 n-tiles x hi/lo) in regs, loaded once.
//   S^T[m',n] = mfma_16x16x32(A=Q, B=K): lane holds P^T[m'=quad*4+rr][n=ln15].
//   p = exp2(s) (q pre-scaled by log2e) -> bf16 -> B-frag of 16x16x16 PV MFMA:
//   O^T[d,n] += V^T[d,m'] * P^T[m',n], V^T A-frags as 8 B loads from vT.
// No LDS / no barriers in the loop. Epilogue (one barrier pair): cross-wave
// O^T reduce, 1/l, then out = gamma*(O/l)@Wv + x with Wv staged in LDS
// during the main loop's shadow.
__global__ __launch_bounds__(512, 2) void attn_kernel(
    const ushort_t* __restrict__ qhg,
    const ushort_t* __restrict__ khg, const ushort_t* __restrict__ klg,
    const ushort_t* __restrict__ vT,
    const float* __restrict__ Wv, const float* __restrict__ x,
    const float* __restrict__ gamma, float* __restrict__ out)
{
    __shared__ float Ored[8][32][65];   // [wave][d][n], stride 65
    __shared__ float Lred[8][64];
    __shared__ float wv[8192];          // Wv [32][256]
    __shared__ float Os[64][33];        // O [n][d]
    __shared__ float linv[64];

    const int tid  = threadIdx.x;
    const int wave = tid >> 6;          // 0..7
    const int lane = tid & 63;
    const int ln15 = lane & 15;
    const int quad = lane >> 4;

    const int b    = blockIdx.x >> 6;
    const int n0   = (blockIdx.x & 63) * 64;
    const int base = b * NTOK;
    const int bb   = b * 131072;        // vT batch offset

    // K fragments in registers (B-operand of S^T): lane needs K[n=t*16+ln15][c=quad*8..+7]
    bf16x8 khf[4], klf[4];
    #pragma unroll
    for (int t = 0; t < 4; ++t) {
        khf[t] = *reinterpret_cast<const bf16x8*>(
            &khg[(base + n0 + t * 16 + ln15) * 32 + quad * 8]);
        klf[t] = *reinterpret_cast<const bf16x8*>(
            &klg[(base + n0 + t * 16 + ln15) * 32 + quad * 8]);
    }

    // stage Wv while the main loop runs (no barrier until epilogue)
    #pragma unroll
    for (int i = 0; i < 16; ++i) wv[tid + i * 512] = Wv[tid + i * 512];

    f32x4 accO[2][4];   // [s01 = d-tile][t = n-tile]
    #pragma unroll
    for (int s01 = 0; s01 < 2; ++s01)
        #pragma unroll
        for (int t = 0; t < 4; ++t)
            accO[s01][t] = (f32x4){0.f, 0.f, 0.f, 0.f};
    float lacc[4] = {0.f, 0.f, 0.f, 0.f};

    // per-wave m walk: m = it*128 + wave*16 + {0..15}, it = 0..31
    const int mbase = wave * 16;
    const ushort_t* qp  = qhg + (size_t)(base + mbase + ln15) * 32 + quad * 8;
    const ushort_t* vp0 = vT + bb + ln15 * 4096 + mbase + quad * 4;
    const ushort_t* vp1 = vp0 + 16 * 4096;

    for (int it = 0; it < 32; ++it) {
        const bf16x8 qf  = *reinterpret_cast<const bf16x8*>(qp);   // A: Q[m=ln15][c]
        const bf16x4 va0 = *reinterpret_cast<const bf16x4*>(vp0);  // A: V^T[d=ln15][m']
        const bf16x4 va1 = *reinterpret_cast<const bf16x4*>(vp1);  // A: V^T[d=16+ln15][m']
        qp  += 128 * 32;
        vp0 += 128;
        vp1 += 128;

        #pragma unroll
        for (int t = 0; t < 4; ++t) {
            // S^T[m'][n] for n-tile t; lane: m'=quad*4+rr, n=t*16+ln15
            f32x4 s = __builtin_amdgcn_mfma_f32_16x16x32_bf16(
                qf, khf[t], (f32x4){0.f, 0.f, 0.f, 0.f}, 0, 0, 0);
            s = __builtin_amdgcn_mfma_f32_16x16x32_bf16(qf, klf[t], s, 0, 0, 0);

            float p0 = fexp2(s[0]);
            float p1 = fexp2(s[1]);
            float p2 = fexp2(s[2]);
            float p3 = fexp2(s[3]);
            lacc[t] += (p0 + p1) + (p2 + p3);

            ushort_t pu[4];
            pu[0] = f2bf(p0);
            pu[1] = f2bf(p1);
            pu[2] = f2bf(p2);
            pu[3] = f2bf(p3);
            const bf16x4 pb = *reinterpret_cast<bf16x4*>(pu);  // B: P^T[m'][n]

            accO[0][t] = mfma16bf(va0, pb, accO[0][t]);
            accO[1][t] = mfma16bf(va1, pb, accO[1][t]);
        }
    }

    // ---- cross-wave reduction ----
    // O^T: lane holds O^T[d = s01*16 + quad*4 + rr][n = t*16 + ln15]
    #pragma unroll
    for (int s01 = 0; s01 < 2; ++s01)
        #pragma unroll
        for (int t = 0; t < 4; ++t)
            #pragma unroll
            for (int rr = 0; rr < 4; ++rr)
                Ored[wave][s01 * 16 + quad * 4 + rr][t * 16 + ln15] = accO[s01][t][rr];

    // denominator: reduce over quads within wave
    #pragma unroll
    for (int t = 0; t < 4; ++t) {
        float v = lacc[t];
        v += __shfl_xor(v, 16);
        v += __shfl_xor(v, 32);
        if (quad == 0) Lred[wave][t * 16 + ln15] = v;
    }
    __syncthreads();

    // O[n][d] = sum over waves; 1/l
    #pragma unroll
    for (int i = 0; i < 4; ++i) {
        int idx = i * 512 + tid;     // 0..2047
        int d = idx & 31;
        int n = idx >> 5;
        float v = (Ored[0][d][n] + Ored[1][d][n]) + (Ored[2][d][n] + Ored[3][d][n])
                + (Ored[4][d][n] + Ored[5][d][n]) + (Ored[6][d][n] + Ored[7][d][n]);
        Os[n][d] = v;
    }
    if (tid < 64) {
        float s = (Lred[0][tid] + Lred[1][tid]) + (Lred[2][tid] + Lred[3][tid])
                + (Lred[4][tid] + Lred[5][tid]) + (Lred[6][tid] + Lred[7][tid]);
        linv[tid] = 1.0f / s;
    }
    __syncthreads();

    // out = gamma*(O/l)@Wv + x ; thread owns col c, 32 rows (half nh)
    const float g  = gamma[0];
    const int   c  = tid & 255;
    const int   nh = (tid >> 8) * 32;
    const int rowb = base + n0 + nh;
    #pragma unroll
    for (int rc = 0; rc < 32; rc += 8) {
        float acc[8];
        #pragma unroll
        for (int rr = 0; rr < 8; ++rr) acc[rr] = 0.f;
        for (int d = 0; d < 32; ++d) {
            float wvd = wv[d * 256 + c];
            #pragma unroll
            for (int rr = 0; rr < 8; ++rr) acc[rr] += Os[nh + rc + rr][d] * wvd;
        }
        #pragma unroll
        for (int rr = 0; rr < 8; ++rr) {
            int row = rowb + rc + rr;
            out[row * 256 + c] = g * acc[rr] * linv[nh + rc + rr] + x[row * 256 + c];
        }
    }
}

extern "C" void kernel_launch(void* const* d_in, const int* in_sizes, int n_in,
                              void* d_out, int out_size, void* d_ws, size_t ws_size,
                              hipStream_t stream)
{
    const float* x     = (const float*)d_in[0];
    const float* Wf    = (const float*)d_in[1];
    const float* Wg    = (const float*)d_in[2];
    const float* Wh    = (const float*)d_in[3];
    const float* Wv    = (const float*)d_in[4];
    const float* gamma = (const float*)d_in[5];
    float* out = (float*)d_out;

    // ws: qh,kh,kl,vT bf16 (1 MB each)
    ushort_t* qh = (ushort_t*)d_ws;
    ushort_t* kh = qh + NROWS * 32;
    ushort_t* kl = kh + NROWS * 32;
    ushort_t* vT = kl + NROWS * 32;

    qkv_kernel<<<dim3(512), dim3(256), 0, stream>>>(x, Wf, Wg, Wh, qh, kh, kl, vT);
    attn_kernel<<<dim3(256), dim3(512), 0, stream>>>(qh, kh, kl, vT, Wv, x, gamma, out);
}

// Round 3
// 112.340 us; speedup vs baseline: 1.1077x; 1.0098x over previous
//
#include <hip/hip_runtime.h>
#include <hip/hip_bf16.h>
#include <stdint.h>

// NonLocalBlock, fp32 in/out. B=4, N=4096, C=256, D=32.
// v9: attn moves to 1024-thr blocks (16 waves = 4 waves/SIMD, same grid 256,
// same matrix/L2 totals -> pure latency-hiding win) with explicit next-iter
// register prefetch; Ored kept at 8 slots via write(w<8)+accumulate(w>=8)
// so LDS stays ~110 KB. qkv/kh/kl/x hi-lo splits switch from RNE f2bf to
// truncation (exact residual, ~40% less split VALU); stored values keep RNE.
// ~90 us of total dur is harness ws-poison fill (fixed overhead).

typedef __attribute__((ext_vector_type(8))) short bf16x8;
typedef __attribute__((ext_vector_type(4))) short bf16x4;
typedef __attribute__((ext_vector_type(4))) float f32x4;
typedef unsigned short ushort_t;

static __device__ __forceinline__ ushort_t f2bf(float f) {
    __hip_bfloat16 h = __float2bfloat16(f);
    return __builtin_bit_cast(ushort_t, h);
}
static __device__ __forceinline__ float bf2f(ushort_t u) {
    return __bfloat162float(__builtin_bit_cast(__hip_bfloat16, u));
}
// truncation split: hi = top 16 bits (no rounding), residual w-hi is exact,
// lo = RNE bf16 of residual. Pair accuracy ~= RNE split; hi costs 1 shr.
static __device__ __forceinline__ void tsplit(float w, ushort_t& hi, ushort_t& lo) {
    uint32_t b = __builtin_bit_cast(uint32_t, w);
    hi = (ushort_t)(b >> 16);
    float hf = __builtin_bit_cast(float, b & 0xFFFF0000u);
    lo = f2bf(w - hf);
}

static __device__ __forceinline__ f32x4 mfma16bf(bf16x4 a, bf16x4 b, f32x4 c) {
#if __has_builtin(__builtin_amdgcn_mfma_f32_16x16x16bf16_1k)
    return __builtin_amdgcn_mfma_f32_16x16x16bf16_1k(a, b, c, 0, 0, 0);
#else
    f32x4 d;
    asm("v_mfma_f32_16x16x16_bf16 %0, %1, %2, %3"
        : "=v"(d) : "v"(a), "v"(b), "v"(c));
    return d;
#endif
}

static __device__ __forceinline__ float fexp2(float x) {
#if __has_builtin(__builtin_amdgcn_exp2f)
    return __builtin_amdgcn_exp2f(x);
#else
    return exp2f(x);
#endif
}

#define NROWS 16384
#define NTOK  4096
#define QKS   40   // q/k LDS row stride (ushorts): 80 B, 16B-aligned (K1 only)
#define LOG2E 1.44269504088896340736f

// ---------------- K1: QKV projection via split-bf16 MFMA ----------------
// 32 rows/block, grid 512 (2 blocks/CU). Wave w: row-group w&1, col-groups
// (w>>1)+{0,2,4}. W fp32 read per-lane (L1/L2-hot), truncation-split in regs.
// q output pre-scaled by log2(e) so attn uses exp2 directly.
__global__ __launch_bounds__(256) void qkv_kernel(
    const float* __restrict__ x,
    const float* __restrict__ Wf, const float* __restrict__ Wg,
    const float* __restrict__ Wh,
    ushort_t* __restrict__ qh,
    ushort_t* __restrict__ kh, ushort_t* __restrict__ kl,
    ushort_t* __restrict__ vT)   // [b][d][m] = [4][32][4096]
{
    __shared__ __align__(16) ushort_t xh[32 * QKS];
    __shared__ __align__(16) ushort_t xl[32 * QKS];

    const int tid  = threadIdx.x;
    const int wave = tid >> 6;
    const int lane = tid & 63;
    const int ln15 = lane & 15;
    const int quad = lane >> 4;
    const int row0 = blockIdx.x * 32;
    const int rg     = wave & 1;
    const int cgbase = wave >> 1;
    const int r  = tid >> 3;        // staging row 0..31
    const int pp = (tid & 7) * 4;   // staging col (floats)

    f32x4 acc[3];
    #pragma unroll
    for (int ci = 0; ci < 3; ++ci) acc[ci] = (f32x4){0.f, 0.f, 0.f, 0.f};

    float4 xa = *reinterpret_cast<const float4*>(&x[(row0 + r) * 256 + pp]);

    for (int k0 = 0; k0 < 256; k0 += 32) {
        // B fragments: read W fp32 directly, truncation-split in registers
        bf16x8 bh[3], bl[3];
        #pragma unroll
        for (int ci = 0; ci < 3; ++ci) {
            int cg = cgbase + ci * 2;
            const float* Wsrc = (cg < 2) ? Wf : (cg < 4) ? Wg : Wh;
            int c = (cg & 1) * 16 + ln15;
            ushort_t hv8[8], lv8[8];
            #pragma unroll
            for (int j = 0; j < 8; ++j) {
                float w = Wsrc[(k0 + quad * 8 + j) * 32 + c];
                tsplit(w, hv8[j], lv8[j]);
            }
            bh[ci] = *reinterpret_cast<bf16x8*>(hv8);
            bl[ci] = *reinterpret_cast<bf16x8*>(lv8);
        }
        // split current x chunk
        float fv[4];
        *reinterpret_cast<float4*>(fv) = xa;
        ushort_t hv[4], lv[4];
        #pragma unroll
        for (int j = 0; j < 4; ++j) tsplit(fv[j], hv[j], lv[j]);
        __syncthreads();
        *reinterpret_cast<uint2*>(&xh[r * QKS + pp]) = *reinterpret_cast<uint2*>(hv);
        *reinterpret_cast<uint2*>(&xl[r * QKS + pp]) = *reinterpret_cast<uint2*>(lv);
        __syncthreads();
        if (k0 < 224)
            xa = *reinterpret_cast<const float4*>(&x[(row0 + r) * 256 + k0 + 32 + pp]);

        const bf16x8 ah = *reinterpret_cast<const bf16x8*>(
            &xh[(rg * 16 + ln15) * QKS + quad * 8]);
        const bf16x8 al = *reinterpret_cast<const bf16x8*>(
            &xl[(rg * 16 + ln15) * QKS + quad * 8]);
        #pragma unroll
        for (int ci = 0; ci < 3; ++ci) {
            acc[ci] = __builtin_amdgcn_mfma_f32_16x16x32_bf16(ah, bh[ci], acc[ci], 0, 0, 0);
            acc[ci] = __builtin_amdgcn_mfma_f32_16x16x32_bf16(al, bh[ci], acc[ci], 0, 0, 0);
            acc[ci] = __builtin_amdgcn_mfma_f32_16x16x32_bf16(ah, bl[ci], acc[ci], 0, 0, 0);
        }
    }

    #pragma unroll
    for (int ci = 0; ci < 3; ++ci) {
        int cg = cgbase + ci * 2;
        int cc = (cg & 1) * 16 + ln15;
        int rowb = row0 + rg * 16 + quad * 4;
        if (cg < 2) {
            #pragma unroll
            for (int rr = 0; rr < 4; ++rr)
                qh[(rowb + rr) * 32 + cc] = f2bf(acc[ci][rr] * LOG2E);
        } else if (cg < 4) {
            #pragma unroll
            for (int rr = 0; rr < 4; ++rr) {
                ushort_t hi, lo;
                tsplit(acc[ci][rr], hi, lo);
                kh[(rowb + rr) * 32 + cc] = hi;
                kl[(rowb + rr) * 32 + cc] = lo;
            }
        } else {
            // V pre-transposed: vT[b][d=cc][m], m = rowb..rowb+3 (same batch)
            int bb = row0 >> 12;
            int m  = (row0 & 4095) + rg * 16 + quad * 4;
            ushort4 h4;
            h4.x = f2bf(acc[ci][0]);
            h4.y = f2bf(acc[ci][1]);
            h4.z = f2bf(acc[ci][2]);
            h4.w = f2bf(acc[ci][3]);
            *reinterpret_cast<ushort4*>(&vT[bb * 131072 + cc * 4096 + m]) = h4;
        }
    }
}

// ---------------- K2: fused attention + output projection ----------------
// Grid 256 = 4 batches x 64 rowtiles, 1024 threads (16 waves, 4 waves/SIMD).
// Wave w owns m-sub 16 of each 256-m iter, 16 iters (full m range). Per wave:
//   K frags (4 n-tiles x hi/lo) in regs, loaded once.
//   S^T[m',n] = mfma_16x16x32(A=Q, B=K): lane holds P^T[m'=quad*4+rr][n=ln15].
//   p = exp2(s) (q pre-scaled by log2e) -> bf16 -> B-frag of 16x16x16 PV MFMA:
//   O^T[d,n] += V^T[d,m'] * P^T[m',n], V^T A-frags as 8 B loads from vT.
// Next-iter Q/V prefetched into regs. No LDS / no barriers in the loop.
// Epilogue: waves 0-7 write Ored/Lred, waves 8-15 accumulate into the same
// slots (keeps LDS at 8 slots ~110 KB), then 1/l and out = gamma*(O/l)@Wv + x.
__global__ __launch_bounds__(1024, 4) void attn_kernel(
    const ushort_t* __restrict__ qhg,
    const ushort_t* __restrict__ khg, const ushort_t* __restrict__ klg,
    const ushort_t* __restrict__ vT,
    const float* __restrict__ Wv, const float* __restrict__ x,
    const float* __restrict__ gamma, float* __restrict__ out)
{
    __shared__ float Ored[8][32][65];   // [slot][d][n], stride 65
    __shared__ float Lred[8][64];
    __shared__ float wv[8192];          // Wv [32][256]
    __shared__ float Os[64][33];        // O [n][d]
    __shared__ float linv[64];

    const int tid  = threadIdx.x;
    const int wave = tid >> 6;          // 0..15
    const int lane = tid & 63;
    const int ln15 = lane & 15;
    const int quad = lane >> 4;

    const int b    = blockIdx.x >> 6;
    const int n0   = (blockIdx.x & 63) * 64;
    const int base = b * NTOK;
    const int bb   = b * 131072;        // vT batch offset

    // K fragments in registers (B-operand of S^T): lane needs K[n=t*16+ln15][c=quad*8..+7]
    bf16x8 khf[4], klf[4];
    #pragma unroll
    for (int t = 0; t < 4; ++t) {
        khf[t] = *reinterpret_cast<const bf16x8*>(
            &khg[(base + n0 + t * 16 + ln15) * 32 + quad * 8]);
        klf[t] = *reinterpret_cast<const bf16x8*>(
            &klg[(base + n0 + t * 16 + ln15) * 32 + quad * 8]);
    }

    // stage Wv while the main loop runs (no barrier until epilogue)
    #pragma unroll
    for (int i = 0; i < 8; ++i) wv[tid + i * 1024] = Wv[tid + i * 1024];

    f32x4 accO[2][4];   // [s01 = d-tile][t = n-tile]
    #pragma unroll
    for (int s01 = 0; s01 < 2; ++s01)
        #pragma unroll
        for (int t = 0; t < 4; ++t)
            accO[s01][t] = (f32x4){0.f, 0.f, 0.f, 0.f};
    float lacc[4] = {0.f, 0.f, 0.f, 0.f};

    // per-wave m walk: m = it*256 + wave*16 + {0..15}, it = 0..15
    const int mbase = wave * 16;
    const ushort_t* qp  = qhg + (size_t)(base + mbase + ln15) * 32 + quad * 8;
    const ushort_t* vp0 = vT + bb + ln15 * 4096 + mbase + quad * 4;
    const ushort_t* vp1 = vp0 + 16 * 4096;

    bf16x8 qf  = *reinterpret_cast<const bf16x8*>(qp);   // A: Q[m=ln15][c]
    bf16x4 va0 = *reinterpret_cast<const bf16x4*>(vp0);  // A: V^T[d=ln15][m']
    bf16x4 va1 = *reinterpret_cast<const bf16x4*>(vp1);  // A: V^T[d=16+ln15][m']

    for (int it = 0; it < 16; ++it) {
        qp  += 256 * 32;
        vp0 += 256;
        vp1 += 256;
        // prefetch next iter (it=15 reads past the 4 MB region but stays well
        // inside the 256 MB workspace; values unused)
        bf16x8 nqf  = *reinterpret_cast<const bf16x8*>(qp);
        bf16x4 nva0 = *reinterpret_cast<const bf16x4*>(vp0);
        bf16x4 nva1 = *reinterpret_cast<const bf16x4*>(vp1);

        #pragma unroll
        for (int t = 0; t < 4; ++t) {
            // S^T[m'][n] for n-tile t; lane: m'=quad*4+rr, n=t*16+ln15
            f32x4 s = __builtin_amdgcn_mfma_f32_16x16x32_bf16(
                qf, khf[t], (f32x4){0.f, 0.f, 0.f, 0.f}, 0, 0, 0);
            s = __builtin_amdgcn_mfma_f32_16x16x32_bf16(qf, klf[t], s, 0, 0, 0);

            float p0 = fexp2(s[0]);
            float p1 = fexp2(s[1]);
            float p2 = fexp2(s[2]);
            float p3 = fexp2(s[3]);
            lacc[t] += (p0 + p1) + (p2 + p3);

            ushort_t pu[4];
            pu[0] = f2bf(p0);
            pu[1] = f2bf(p1);
            pu[2] = f2bf(p2);
            pu[3] = f2bf(p3);
            const bf16x4 pb = *reinterpret_cast<bf16x4*>(pu);  // B: P^T[m'][n]

            accO[0][t] = mfma16bf(va0, pb, accO[0][t]);
            accO[1][t] = mfma16bf(va1, pb, accO[1][t]);
        }
        qf = nqf; va0 = nva0; va1 = nva1;
    }

    // ---- cross-wave reduction ----
    // lane holds O^T[d = s01*16 + quad*4 + rr][n = t*16 + ln15]
    float lr[4];
    #pragma unroll
    for (int t = 0; t < 4; ++t) {
        float v = lacc[t];
        v += __shfl_xor(v, 16);
        v += __shfl_xor(v, 32);
        lr[t] = v;
    }
    if (wave < 8) {
        #pragma unroll
        for (int s01 = 0; s01 < 2; ++s01)
            #pragma unroll
            for (int t = 0; t < 4; ++t)
                #pragma unroll
                for (int rr = 0; rr < 4; ++rr)
                    Ored[wave][s01 * 16 + quad * 4 + rr][t * 16 + ln15] = accO[s01][t][rr];
        if (quad == 0) {
            #pragma unroll
            for (int t = 0; t < 4; ++t) Lred[wave][t * 16 + ln15] = lr[t];
        }
    }
    __syncthreads();
    if (wave >= 8) {
        const int ws = wave - 8;
        #pragma unroll
        for (int s01 = 0; s01 < 2; ++s01)
            #pragma unroll
            for (int t = 0; t < 4; ++t)
                #pragma unroll
                for (int rr = 0; rr < 4; ++rr)
                    Ored[ws][s01 * 16 + quad * 4 + rr][t * 16 + ln15] += accO[s01][t][rr];
        if (quad == 0) {
            #pragma unroll
            for (int t = 0; t < 4; ++t) Lred[ws][t * 16 + ln15] += lr[t];
        }
    }
    __syncthreads();

    // O[n][d] = sum over 8 slots; 1/l
    #pragma unroll
    for (int i = 0; i < 2; ++i) {
        int idx = i * 1024 + tid;     // 0..2047
        int d = idx & 31;
        int n = idx >> 5;
        float v = (Ored[0][d][n] + Ored[1][d][n]) + (Ored[2][d][n] + Ored[3][d][n])
                + (Ored[4][d][n] + Ored[5][d][n]) + (Ored[6][d][n] + Ored[7][d][n]);
        Os[n][d] = v;
    }
    if (tid < 64) {
        float s = (Lred[0][tid] + Lred[1][tid]) + (Lred[2][tid] + Lred[3][tid])
                + (Lred[4][tid] + Lred[5][tid]) + (Lred[6][tid] + Lred[7][tid]);
        linv[tid] = 1.0f / s;
    }
    __syncthreads();

    // out = gamma*(O/l)@Wv + x ; thread owns col c, 16 rows (quarter nh)
    const float g  = gamma[0];
    const int   c  = tid & 255;
    const int   nh = (tid >> 8) * 16;
    const int rowb = base + n0 + nh;
    #pragma unroll
    for (int rc = 0; rc < 16; rc += 8) {
        float acc[8];
        #pragma unroll
        for (int rr = 0; rr < 8; ++rr) acc[rr] = 0.f;
        for (int d = 0; d < 32; ++d) {
            float wvd = wv[d * 256 + c];
            #pragma unroll
            for (int rr = 0; rr < 8; ++rr) acc[rr] += Os[nh + rc + rr][d] * wvd;
        }
        #pragma unroll
        for (int rr = 0; rr < 8; ++rr) {
            int row = rowb + rc + rr;
            out[row * 256 + c] = g * acc[rr] * linv[nh + rc + rr] + x[row * 256 + c];
        }
    }
}

extern "C" void kernel_launch(void* const* d_in, const int* in_sizes, int n_in,
                              void* d_out, int out_size, void* d_ws, size_t ws_size,
                              hipStream_t stream)
{
    const float* x     = (const float*)d_in[0];
    const float* Wf    = (const float*)d_in[1];
    const float* Wg    = (const float*)d_in[2];
    const float* Wh    = (const float*)d_in[3];
    const float* Wv    = (const float*)d_in[4];
    const float* gamma = (const float*)d_in[5];
    float* out = (float*)d_out;

    // ws: qh,kh,kl,vT bf16 (1 MB each)
    ushort_t* qh = (ushort_t*)d_ws;
    ushort_t* kh = qh + NROWS * 32;
    ushort_t* kl = kh + NROWS * 32;
    ushort_t* vT = kl + NROWS * 32;

    qkv_kernel<<<dim3(512), dim3(256), 0, stream>>>(x, Wf, Wg, Wh, qh, kh, kl, vT);
    attn_kernel<<<dim3(256), dim3(1024), 0, stream>>>(qh, kh, kl, vT, Wv, x, gamma, out);
}

// Round 4
// 112.127 us; speedup vs baseline: 1.1098x; 1.0019x over previous
//
#include <hip/hip_runtime.h>
#include <hip/hip_bf16.h>
#include <stdint.h>

// NonLocalBlock, fp32 in/out. B=4, N=4096, C=256, D=32.
// v10: q/k move to fp16 storage (2^-11 rel vs bf16 2^-9; S error improves 2x).
// kl array eliminated entirely: QK^T is ONE v_mfma_f32_16x16x32_f16 per tile
// (was two bf16 MFMAs), qkv loses the k split + second store (-1 MB HBM).
// P stays bf16 (unnormalized P reaches 2^36 -> fp16 would overflow); PV MFMAs
// unchanged. x@W keeps the split-bf16 3-MFMA scheme for source precision.
// Main loop stays barrier-free / LDS-free. ~90 us of dur is harness ws-poison.

typedef __attribute__((ext_vector_type(8))) short bf16x8;
typedef __attribute__((ext_vector_type(4))) short bf16x4;
typedef __attribute__((ext_vector_type(8))) _Float16 f16x8;
typedef __attribute__((ext_vector_type(4))) float f32x4;
typedef unsigned short ushort_t;

static __device__ __forceinline__ ushort_t f2bf(float f) {
    __hip_bfloat16 h = __float2bfloat16(f);
    return __builtin_bit_cast(ushort_t, h);
}
static __device__ __forceinline__ float bf2f(ushort_t u) {
    return __bfloat162float(__builtin_bit_cast(__hip_bfloat16, u));
}
static __device__ __forceinline__ ushort_t f2h(float f) {
    _Float16 h = (_Float16)f;            // RNE v_cvt_f16_f32
    return __builtin_bit_cast(ushort_t, h);
}
// truncation split: hi = top 16 bits (no rounding), residual w-hi is exact,
// lo = RNE bf16 of residual.
static __device__ __forceinline__ void tsplit(float w, ushort_t& hi, ushort_t& lo) {
    uint32_t b = __builtin_bit_cast(uint32_t, w);
    hi = (ushort_t)(b >> 16);
    float hf = __builtin_bit_cast(float, b & 0xFFFF0000u);
    lo = f2bf(w - hf);
}

static __device__ __forceinline__ f32x4 mfma16bf(bf16x4 a, bf16x4 b, f32x4 c) {
#if __has_builtin(__builtin_amdgcn_mfma_f32_16x16x16bf16_1k)
    return __builtin_amdgcn_mfma_f32_16x16x16bf16_1k(a, b, c, 0, 0, 0);
#else
    f32x4 d;
    asm("v_mfma_f32_16x16x16_bf16 %0, %1, %2, %3"
        : "=v"(d) : "v"(a), "v"(b), "v"(c));
    return d;
#endif
}

static __device__ __forceinline__ float fexp2(float x) {
#if __has_builtin(__builtin_amdgcn_exp2f)
    return __builtin_amdgcn_exp2f(x);
#else
    return exp2f(x);
#endif
}

#define NROWS 16384
#define NTOK  4096
#define QKS   40   // q/k LDS row stride (ushorts): 80 B, 16B-aligned (K1 only)
#define LOG2E 1.44269504088896340736f

// ---------------- K1: QKV projection via split-bf16 MFMA ----------------
// 32 rows/block, grid 512 (2 blocks/CU). Wave w: row-group w&1, col-groups
// (w>>1)+{0,2,4}. W fp32 read per-lane (L1/L2-hot), truncation-split in regs.
// q output pre-scaled by log2(e); q and k stored fp16, v bf16 transposed.
__global__ __launch_bounds__(256) void qkv_kernel(
    const float* __restrict__ x,
    const float* __restrict__ Wf, const float* __restrict__ Wg,
    const float* __restrict__ Wh,
    ushort_t* __restrict__ qh,   // fp16 [b*n][32], pre-scaled by log2(e)
    ushort_t* __restrict__ kf,   // fp16 [b*n][32]
    ushort_t* __restrict__ vT)   // bf16 [b][d][m] = [4][32][4096]
{
    __shared__ __align__(16) ushort_t xh[32 * QKS];
    __shared__ __align__(16) ushort_t xl[32 * QKS];

    const int tid  = threadIdx.x;
    const int wave = tid >> 6;
    const int lane = tid & 63;
    const int ln15 = lane & 15;
    const int quad = lane >> 4;
    const int row0 = blockIdx.x * 32;
    const int rg     = wave & 1;
    const int cgbase = wave >> 1;
    const int r  = tid >> 3;        // staging row 0..31
    const int pp = (tid & 7) * 4;   // staging col (floats)

    f32x4 acc[3];
    #pragma unroll
    for (int ci = 0; ci < 3; ++ci) acc[ci] = (f32x4){0.f, 0.f, 0.f, 0.f};

    float4 xa = *reinterpret_cast<const float4*>(&x[(row0 + r) * 256 + pp]);

    for (int k0 = 0; k0 < 256; k0 += 32) {
        // B fragments: read W fp32 directly, truncation-split in registers
        bf16x8 bh[3], bl[3];
        #pragma unroll
        for (int ci = 0; ci < 3; ++ci) {
            int cg = cgbase + ci * 2;
            const float* Wsrc = (cg < 2) ? Wf : (cg < 4) ? Wg : Wh;
            int c = (cg & 1) * 16 + ln15;
            ushort_t hv8[8], lv8[8];
            #pragma unroll
            for (int j = 0; j < 8; ++j) {
                float w = Wsrc[(k0 + quad * 8 + j) * 32 + c];
                tsplit(w, hv8[j], lv8[j]);
            }
            bh[ci] = *reinterpret_cast<bf16x8*>(hv8);
            bl[ci] = *reinterpret_cast<bf16x8*>(lv8);
        }
        // split current x chunk
        float fv[4];
        *reinterpret_cast<float4*>(fv) = xa;
        ushort_t hv[4], lv[4];
        #pragma unroll
        for (int j = 0; j < 4; ++j) tsplit(fv[j], hv[j], lv[j]);
        __syncthreads();
        *reinterpret_cast<uint2*>(&xh[r * QKS + pp]) = *reinterpret_cast<uint2*>(hv);
        *reinterpret_cast<uint2*>(&xl[r * QKS + pp]) = *reinterpret_cast<uint2*>(lv);
        __syncthreads();
        if (k0 < 224)
            xa = *reinterpret_cast<const float4*>(&x[(row0 + r) * 256 + k0 + 32 + pp]);

        const bf16x8 ah = *reinterpret_cast<const bf16x8*>(
            &xh[(rg * 16 + ln15) * QKS + quad * 8]);
        const bf16x8 al = *reinterpret_cast<const bf16x8*>(
            &xl[(rg * 16 + ln15) * QKS + quad * 8]);
        #pragma unroll
        for (int ci = 0; ci < 3; ++ci) {
            acc[ci] = __builtin_amdgcn_mfma_f32_16x16x32_bf16(ah, bh[ci], acc[ci], 0, 0, 0);
            acc[ci] = __builtin_amdgcn_mfma_f32_16x16x32_bf16(al, bh[ci], acc[ci], 0, 0, 0);
            acc[ci] = __builtin_amdgcn_mfma_f32_16x16x32_bf16(ah, bl[ci], acc[ci], 0, 0, 0);
        }
    }

    #pragma unroll
    for (int ci = 0; ci < 3; ++ci) {
        int cg = cgbase + ci * 2;
        int cc = (cg & 1) * 16 + ln15;
        int rowb = row0 + rg * 16 + quad * 4;
        if (cg < 2) {
            #pragma unroll
            for (int rr = 0; rr < 4; ++rr)
                qh[(rowb + rr) * 32 + cc] = f2h(acc[ci][rr] * LOG2E);
        } else if (cg < 4) {
            #pragma unroll
            for (int rr = 0; rr < 4; ++rr)
                kf[(rowb + rr) * 32 + cc] = f2h(acc[ci][rr]);
        } else {
            // V pre-transposed: vT[b][d=cc][m], m = rowb..rowb+3 (same batch)
            int bb = row0 >> 12;
            int m  = (row0 & 4095) + rg * 16 + quad * 4;
            ushort4 h4;
            h4.x = f2bf(acc[ci][0]);
            h4.y = f2bf(acc[ci][1]);
            h4.z = f2bf(acc[ci][2]);
            h4.w = f2bf(acc[ci][3]);
            *reinterpret_cast<ushort4*>(&vT[bb * 131072 + cc * 4096 + m]) = h4;
        }
    }
}

// ---------------- K2: fused attention + output projection ----------------
// Grid 256 = 4 batches x 64 rowtiles, 1024 threads (16 waves, 4 waves/SIMD).
// Wave w owns m-sub 16 of each 256-m iter, 16 iters (full m range). Per wave:
//   K frags (4 n-tiles, fp16) in regs, loaded once.
//   S^T[m',n] = one mfma_16x16x32_f16(A=Q, B=K): lane holds P^T[m'][n=ln15].
//   p = exp2(s) (q pre-scaled by log2e) -> bf16 -> B-frag of 16x16x16 PV MFMA:
//   O^T[d,n] += V^T[d,m'] * P^T[m',n], V^T A-frags as 8 B loads from vT.
// Next-iter Q/V prefetched into regs. No LDS / no barriers in the loop.
// Epilogue: waves 0-7 write Ored/Lred, waves 8-15 accumulate into the same
// slots, then 1/l and out = gamma*(O/l)@Wv + x with Wv LDS-staged.
__global__ __launch_bounds__(1024, 4) void attn_kernel(
    const ushort_t* __restrict__ qhg,
    const ushort_t* __restrict__ kfg,
    const ushort_t* __restrict__ vT,
    const float* __restrict__ Wv, const float* __restrict__ x,
    const float* __restrict__ gamma, float* __restrict__ out)
{
    __shared__ float Ored[8][32][65];   // [slot][d][n], stride 65
    __shared__ float Lred[8][64];
    __shared__ float wv[8192];          // Wv [32][256]
    __shared__ float Os[64][33];        // O [n][d]
    __shared__ float linv[64];

    const int tid  = threadIdx.x;
    const int wave = tid >> 6;          // 0..15
    const int lane = tid & 63;
    const int ln15 = lane & 15;
    const int quad = lane >> 4;

    const int b    = blockIdx.x >> 6;
    const int n0   = (blockIdx.x & 63) * 64;
    const int base = b * NTOK;
    const int bb   = b * 131072;        // vT batch offset

    // K fragments in registers (B-operand of S^T): lane needs K[n=t*16+ln15][c=quad*8..+7]
    f16x8 khf[4];
    #pragma unroll
    for (int t = 0; t < 4; ++t)
        khf[t] = *reinterpret_cast<const f16x8*>(
            &kfg[(base + n0 + t * 16 + ln15) * 32 + quad * 8]);

    // stage Wv while the main loop runs (no barrier until epilogue)
    #pragma unroll
    for (int i = 0; i < 8; ++i) wv[tid + i * 1024] = Wv[tid + i * 1024];

    f32x4 accO[2][4];   // [s01 = d-tile][t = n-tile]
    #pragma unroll
    for (int s01 = 0; s01 < 2; ++s01)
        #pragma unroll
        for (int t = 0; t < 4; ++t)
            accO[s01][t] = (f32x4){0.f, 0.f, 0.f, 0.f};
    float lacc[4] = {0.f, 0.f, 0.f, 0.f};

    // per-wave m walk: m = it*256 + wave*16 + {0..15}, it = 0..15
    const int mbase = wave * 16;
    const ushort_t* qp  = qhg + (size_t)(base + mbase + ln15) * 32 + quad * 8;
    const ushort_t* vp0 = vT + bb + ln15 * 4096 + mbase + quad * 4;
    const ushort_t* vp1 = vp0 + 16 * 4096;

    f16x8  qf  = *reinterpret_cast<const f16x8*>(qp);    // A: Q[m=ln15][c]
    bf16x4 va0 = *reinterpret_cast<const bf16x4*>(vp0);  // A: V^T[d=ln15][m']
    bf16x4 va1 = *reinterpret_cast<const bf16x4*>(vp1);  // A: V^T[d=16+ln15][m']

    for (int it = 0; it < 16; ++it) {
        qp  += 256 * 32;
        vp0 += 256;
        vp1 += 256;
        // prefetch next iter (it=15 reads past the 3 MB region but stays well
        // inside the 256 MB workspace; values unused)
        f16x8  nqf  = *reinterpret_cast<const f16x8*>(qp);
        bf16x4 nva0 = *reinterpret_cast<const bf16x4*>(vp0);
        bf16x4 nva1 = *reinterpret_cast<const bf16x4*>(vp1);

        #pragma unroll
        for (int t = 0; t < 4; ++t) {
            // S^T[m'][n] for n-tile t; lane: m'=quad*4+rr, n=t*16+ln15
            f32x4 s = __builtin_amdgcn_mfma_f32_16x16x32_f16(
                qf, khf[t], (f32x4){0.f, 0.f, 0.f, 0.f}, 0, 0, 0);

            float p0 = fexp2(s[0]);
            float p1 = fexp2(s[1]);
            float p2 = fexp2(s[2]);
            float p3 = fexp2(s[3]);
            lacc[t] += (p0 + p1) + (p2 + p3);

            ushort_t pu[4];
            pu[0] = f2bf(p0);
            pu[1] = f2bf(p1);
            pu[2] = f2bf(p2);
            pu[3] = f2bf(p3);
            const bf16x4 pb = *reinterpret_cast<bf16x4*>(pu);  // B: P^T[m'][n]

            accO[0][t] = mfma16bf(va0, pb, accO[0][t]);
            accO[1][t] = mfma16bf(va1, pb, accO[1][t]);
        }
        qf = nqf; va0 = nva0; va1 = nva1;
    }

    // ---- cross-wave reduction ----
    // lane holds O^T[d = s01*16 + quad*4 + rr][n = t*16 + ln15]
    float lr[4];
    #pragma unroll
    for (int t = 0; t < 4; ++t) {
        float v = lacc[t];
        v += __shfl_xor(v, 16);
        v += __shfl_xor(v, 32);
        lr[t] = v;
    }
    if (wave < 8) {
        #pragma unroll
        for (int s01 = 0; s01 < 2; ++s01)
            #pragma unroll
            for (int t = 0; t < 4; ++t)
                #pragma unroll
                for (int rr = 0; rr < 4; ++rr)
                    Ored[wave][s01 * 16 + quad * 4 + rr][t * 16 + ln15] = accO[s01][t][rr];
        if (quad == 0) {
            #pragma unroll
            for (int t = 0; t < 4; ++t) Lred[wave][t * 16 + ln15] = lr[t];
        }
    }
    __syncthreads();
    if (wave >= 8) {
        const int ws = wave - 8;
        #pragma unroll
        for (int s01 = 0; s01 < 2; ++s01)
            #pragma unroll
            for (int t = 0; t < 4; ++t)
                #pragma unroll
                for (int rr = 0; rr < 4; ++rr)
                    Ored[ws][s01 * 16 + quad * 4 + rr][t * 16 + ln15] += accO[s01][t][rr];
        if (quad == 0) {
            #pragma unroll
            for (int t = 0; t < 4; ++t) Lred[ws][t * 16 + ln15] += lr[t];
        }
    }
    __syncthreads();

    // O[n][d] = sum over 8 slots; 1/l
    #pragma unroll
    for (int i = 0; i < 2; ++i) {
        int idx = i * 1024 + tid;     // 0..2047
        int d = idx & 31;
        int n = idx >> 5;
        float v = (Ored[0][d][n] + Ored[1][d][n]) + (Ored[2][d][n] + Ored[3][d][n])
                + (Ored[4][d][n] + Ored[5][d][n]) + (Ored[6][d][n] + Ored[7][d][n]);
        Os[n][d] = v;
    }
    if (tid < 64) {
        float s = (Lred[0][tid] + Lred[1][tid]) + (Lred[2][tid] + Lred[3][tid])
                + (Lred[4][tid] + Lred[5][tid]) + (Lred[6][tid] + Lred[7][tid]);
        linv[tid] = 1.0f / s;
    }
    __syncthreads();

    // out = gamma*(O/l)@Wv + x ; thread owns col c, 16 rows (quarter nh)
    const float g  = gamma[0];
    const int   c  = tid & 255;
    const int   nh = (tid >> 8) * 16;
    const int rowb = base + n0 + nh;
    #pragma unroll
    for (int rc = 0; rc < 16; rc += 8) {
        float acc[8];
        #pragma unroll
        for (int rr = 0; rr < 8; ++rr) acc[rr] = 0.f;
        for (int d = 0; d < 32; ++d) {
            float wvd = wv[d * 256 + c];
            #pragma unroll
            for (int rr = 0; rr < 8; ++rr) acc[rr] += Os[nh + rc + rr][d] * wvd;
        }
        #pragma unroll
        for (int rr = 0; rr < 8; ++rr) {
            int row = rowb + rc + rr;
            out[row * 256 + c] = g * acc[rr] * linv[nh + rc + rr] + x[row * 256 + c];
        }
    }
}

extern "C" void kernel_launch(void* const* d_in, const int* in_sizes, int n_in,
                              void* d_out, int out_size, void* d_ws, size_t ws_size,
                              hipStream_t stream)
{
    const float* x     = (const float*)d_in[0];
    const float* Wf    = (const float*)d_in[1];
    const float* Wg    = (const float*)d_in[2];
    const float* Wh    = (const float*)d_in[3];
    const float* Wv    = (const float*)d_in[4];
    const float* gamma = (const float*)d_in[5];
    float* out = (float*)d_out;

    // ws: qh (fp16), kf (fp16), vT (bf16) — 1 MB each
    ushort_t* qh = (ushort_t*)d_ws;
    ushort_t* kf = qh + NROWS * 32;
    ushort_t* vT = kf + NROWS * 32;

    qkv_kernel<<<dim3(512), dim3(256), 0, stream>>>(x, Wf, Wg, Wh, qh, kf, vT);
    attn_kernel<<<dim3(256), dim3(1024), 0, stream>>>(qh, kf, vT, Wv, x, gamma, out);
}